// Round 1
// baseline (697.894 us; speedup 1.0000x reference)
//
#include <hip/hip_runtime.h>
#include <hip/hip_bf16.h>
#include <stdint.h>

typedef unsigned short u16;
typedef __attribute__((ext_vector_type(8))) short short8;
typedef __attribute__((ext_vector_type(8))) unsigned short u16x8;
typedef __attribute__((ext_vector_type(4))) float f32x4;

#define B_    2
#define S_    2048
#define H_    32
#define HKV_  8
#define D_    128
#define HID_  4096
#define QKVW_ 6144

__device__ __forceinline__ u16 f2bf(float f){
  uint32_t b = __builtin_bit_cast(uint32_t, f);
  b += 0x7FFFu + ((b >> 16) & 1u);
  return (u16)(b >> 16);
}
__device__ __forceinline__ float bf2f(u16 h){
  uint32_t b = ((uint32_t)h) << 16;
  return __builtin_bit_cast(float, b);
}

__device__ __forceinline__ void gload16(const u16* g, u16* l){
  __builtin_amdgcn_global_load_lds((const __attribute__((address_space(1))) void*)g,
                                   (__attribute__((address_space(3))) void*)l, 16, 0, 0);
}

// ---------------- fp32 -> bf16 convert ----------------
__global__ void cvt_kernel(const float* __restrict__ src, u16* __restrict__ dst, int n4){
  int i = blockIdx.x * blockDim.x + threadIdx.x;
  int stride = gridDim.x * blockDim.x;
  for (; i < n4; i += stride){
    float4 v = reinterpret_cast<const float4*>(src)[i];
    union { u16 u[4]; unsigned long long ll; } o;
    o.u[0] = f2bf(v.x); o.u[1] = f2bf(v.y); o.u[2] = f2bf(v.z); o.u[3] = f2bf(v.w);
    reinterpret_cast<unsigned long long*>(dst)[i] = o.ll;
  }
}

// ---------------- RoPE table: tab[pos*64+p] = (cos, sin) ----------------
__global__ void rope_table_kernel(float2* __restrict__ tab){
  int idx = blockIdx.x * blockDim.x + threadIdx.x;
  if (idx >= S_ * 64) return;
  int pos = idx >> 6, p = idx & 63;
  float inv = powf(10000.0f, -(float)p / 64.0f);
  float ang = (float)pos * inv;
  tab[idx] = make_float2(cosf(ang), sinf(ang));
}

// ---------------- RoPE apply (in-place on bf16 qkv); Q gets scale*log2e folded ----------------
__global__ void rope_apply_kernel(u16* __restrict__ qkv, const int* __restrict__ pos_ids,
                                  const float2* __restrict__ tab){
  const float QS = 0.08838834764831845f * 1.4426950408889634f; // 1/sqrt(128) * log2(e)
  int t = blockIdx.x;
  int pos = pos_ids[t];
  const float2* tb = tab + pos * 64;
  u16* row = qkv + (size_t)t * QKVW_;
  for (int it = threadIdx.x; it < (H_ + HKV_) * 64; it += 256){
    int hh = it >> 6, p = it & 63;
    int base = (hh < H_) ? hh * D_ : HID_ + (hh - H_) * D_;
    float sc = (hh < H_) ? QS : 1.0f;
    float x1 = bf2f(row[base + p]);
    float x2 = bf2f(row[base + 64 + p]);
    float2 cs = tb[p];
    row[base + p]      = f2bf((x1 * cs.x - x2 * cs.y) * sc);
    row[base + 64 + p] = f2bf((x2 * cs.x + x1 * cs.y) * sc);
  }
}

// ---------------- bf16 GEMM: C[M][N] = A[M][K] * B[N][K]^T ----------------
// CF==0: bf16 output, CF==1: fp32 output
template<int CF>
__global__ __launch_bounds__(256) void gemm_bt(const u16* __restrict__ A, const u16* __restrict__ B,
                                               void* __restrict__ Cv, int M, int N, int K){
  __shared__ u16 As[128*64];
  __shared__ u16 Bs[128*64];
  const int tid  = threadIdx.x;
  const int wave = tid >> 6, lane = tid & 63;
  const int hi = lane >> 4, lo = lane & 15;
  const int bn = blockIdx.x, bm = blockIdx.y;
  const int wm = (wave >> 1) * 64, wn = (wave & 1) * 64;
  f32x4 acc[4][4] = {};

  // staging: linear LDS dest (global_load_lds), inverse-swizzled global source.
  const u16* ap[4]; const u16* bp[4];
  u16* lA[4]; u16* lB[4];
  #pragma unroll
  for (int p = 0; p < 4; p++){
    int e   = p*2048 + wave*512 + lane*8;       // linear elem offset in tile
    int row = e >> 6;                           // tile row (BK=64 elems/row)
    int cs  = ((e >> 3) & 7) ^ (row & 7);       // swizzled col8
    ap[p] = A + (size_t)(bm*128 + row) * K + cs*8;
    bp[p] = B + (size_t)(bn*128 + row) * K + cs*8;
    lA[p] = &As[p*2048 + wave*512];
    lB[p] = &Bs[p*2048 + wave*512];
  }
  const int sw = lo & 7;
  const int nk = K >> 6;
  for (int t = 0; t < nk; t++){
    #pragma unroll
    for (int p = 0; p < 4; p++){
      gload16(ap[p], lA[p]);
      gload16(bp[p], lB[p]);
      ap[p] += 64; bp[p] += 64;
    }
    __syncthreads();
    #pragma unroll
    for (int kk = 0; kk < 2; kk++){
      short8 af[4], bf[4];
      int sz = ((kk*4 + hi) ^ sw) * 8;
      #pragma unroll
      for (int mt = 0; mt < 4; mt++) af[mt] = *(const short8*)&As[(wm + mt*16 + lo)*64 + sz];
      #pragma unroll
      for (int nt = 0; nt < 4; nt++) bf[nt] = *(const short8*)&Bs[(wn + nt*16 + lo)*64 + sz];
      #pragma unroll
      for (int mt = 0; mt < 4; mt++)
        #pragma unroll
        for (int nt = 0; nt < 4; nt++)
          acc[mt][nt] = __builtin_amdgcn_mfma_f32_16x16x32_bf16(af[mt], bf[nt], acc[mt][nt], 0, 0, 0);
    }
    __syncthreads();
  }
  #pragma unroll
  for (int mt = 0; mt < 4; mt++){
    int row = bm*128 + wm + mt*16 + 4*hi;
    #pragma unroll
    for (int nt = 0; nt < 4; nt++){
      int col = bn*128 + wn + nt*16 + lo;
      #pragma unroll
      for (int r = 0; r < 4; r++){
        if (CF == 0) ((u16*)Cv)[(size_t)(row + r)*N + col] = f2bf(acc[mt][nt][r]);
        else         ((float*)Cv)[(size_t)(row + r)*N + col] = acc[mt][nt][r];
      }
    }
  }
}

// ---------------- fused windowed-causal GQA flash attention ----------------
// block = (qtile of 64 rows, head h, batch b); 4 waves x 16 q-rows each.
__global__ __launch_bounds__(256) void attn_kernel(const u16* __restrict__ qkv, u16* __restrict__ out,
                                                   const int* __restrict__ winp){
  const int qt = blockIdx.x, h = blockIdx.y, b = blockIdx.z;
  const int hkv = h >> 2;            // G = 4
  const int q0 = qt * 64;
  const int tid = threadIdx.x, wave = tid >> 6, lane = tid & 63;
  const int hi = lane >> 4, lo = lane & 15;
  const int win = winp[0];
  __shared__ u16 Ks[32*136];         // K chunk, padded pitch 136
  __shared__ uint32_t VT[128*20];    // V chunk transposed, u32-packed j-pairs, pitch 20 u32 (=40 bf16)
  __shared__ u16 Pl[4][16*40];       // per-wave P tile

  short8 qf[4];                      // Q fragments (scale*log2e pre-folded by rope kernel)
  {
    const u16* qp = qkv + (size_t)(b*S_ + q0 + wave*16 + lo) * QKVW_ + h*D_ + hi*8;
    #pragma unroll
    for (int c = 0; c < 4; c++) qf[c] = *(const short8*)(qp + c*32);
  }
  f32x4 accO[8] = {};
  float m_r[4] = {-3e38f,-3e38f,-3e38f,-3e38f};
  float l_r[4] = {0.f,0.f,0.f,0.f};

  int js = q0 - (win - 1); if (js < 0) js = 0; js &= ~31;
  const int qw = q0 + wave*16;
  const u16* Kg = qkv + HID_ + hkv*D_;
  const u16* Vg = qkv + HID_ + HKV_*D_ + hkv*D_;
  const int jpv = tid & 15, d0v = (tid >> 4) * 8;

  for (int jc = js; jc < q0 + 64; jc += 32){
    __syncthreads();
    // stage K chunk [32][128] -> Ks padded
    #pragma unroll
    for (int p = 0; p < 2; p++){
      int e = (tid + p*256) * 8;
      int row = e >> 7, col = e & 127;
      *(u16x8*)&Ks[row*136 + col] = *(const u16x8*)(Kg + (size_t)(b*S_ + jc + row)*QKVW_ + col);
    }
    // stage V chunk transposed: VT16[d*40 + j] = V[jc+j][d]
    {
      const u16* v0p = Vg + (size_t)(b*S_ + jc + 2*jpv)*QKVW_ + d0v;
      u16x8 va = *(const u16x8*)v0p;
      u16x8 vb = *(const u16x8*)(v0p + QKVW_);
      #pragma unroll
      for (int i = 0; i < 8; i++)
        VT[(d0v + i)*20 + jpv] = (uint32_t)va[i] | ((uint32_t)vb[i] << 16);
    }
    __syncthreads();
    if (jc <= qw + 15 && jc + 31 >= qw - (win - 1)){
      // QK^T: S[16q][32j] per wave
      f32x4 s[2] = {};
      #pragma unroll
      for (int jt = 0; jt < 2; jt++)
        #pragma unroll
        for (int c = 0; c < 4; c++){
          short8 kf = *(const short8*)&Ks[(jt*16 + lo)*136 + c*32 + hi*8];
          s[jt] = __builtin_amdgcn_mfma_f32_16x16x32_bf16(qf[c], kf, s[jt], 0, 0, 0);
        }
      // mask (finite -3e38; avoids NaN in all-masked rows)
      #pragma unroll
      for (int jt = 0; jt < 2; jt++){
        int j_abs = jc + jt*16 + lo;
        #pragma unroll
        for (int r = 0; r < 4; r++){
          int qa = qw + 4*hi + r;
          if (j_abs > qa || qa - j_abs >= win) s[jt][r] = -3.0e38f;
        }
      }
      // online softmax (log2 domain)
      float alpha[4], ps[4];
      #pragma unroll
      for (int r = 0; r < 4; r++){
        float mx = fmaxf(s[0][r], s[1][r]);
        #pragma unroll
        for (int d = 1; d < 16; d <<= 1) mx = fmaxf(mx, __shfl_xor(mx, d));
        float mn = fmaxf(m_r[r], mx);
        alpha[r] = exp2f(m_r[r] - mn);
        m_r[r] = mn;
        ps[r] = 0.f;
      }
      #pragma unroll
      for (int jt = 0; jt < 2; jt++)
        #pragma unroll
        for (int r = 0; r < 4; r++){
          float sv = s[jt][r];
          float p = (sv > -1.0e37f) ? exp2f(sv - m_r[r]) : 0.0f;
          ps[r] += p;
          Pl[wave][(4*hi + r)*40 + jt*16 + lo] = f2bf(p);
        }
      #pragma unroll
      for (int r = 0; r < 4; r++){
        #pragma unroll
        for (int d = 1; d < 16; d <<= 1) ps[r] += __shfl_xor(ps[r], d);
        l_r[r] = l_r[r]*alpha[r] + ps[r];
      }
      #pragma unroll
      for (int dt = 0; dt < 8; dt++){
        accO[dt][0] *= alpha[0]; accO[dt][1] *= alpha[1];
        accO[dt][2] *= alpha[2]; accO[dt][3] *= alpha[3];
      }
      // PV (wave-internal P round-trip; force LDS drain before reads)
      asm volatile("s_waitcnt lgkmcnt(0)" ::: "memory");
      __builtin_amdgcn_sched_barrier(0);
      short8 pa = *(const short8*)&Pl[wave][lo*40 + hi*8];
      const u16* VT16 = (const u16*)VT;
      #pragma unroll
      for (int dt = 0; dt < 8; dt++){
        short8 vf = *(const short8*)&VT16[(dt*16 + lo)*40 + hi*8];
        accO[dt] = __builtin_amdgcn_mfma_f32_16x16x32_bf16(pa, vf, accO[dt], 0, 0, 0);
      }
    }
  }
  #pragma unroll
  for (int r = 0; r < 4; r++){
    float invl = 1.0f / l_r[r];
    int trow = b*S_ + q0 + wave*16 + 4*hi + r;
    #pragma unroll
    for (int dt = 0; dt < 8; dt++)
      out[(size_t)trow*HID_ + h*D_ + dt*16 + lo] = f2bf(accO[dt][r] * invl);
  }
}

extern "C" void kernel_launch(void* const* d_in, const int* in_sizes, int n_in,
                              void* d_out, int out_size, void* d_ws, size_t ws_size,
                              hipStream_t stream) {
  const float* hs   = (const float*)d_in[0];
  const float* wqkv = (const float*)d_in[1];
  const float* wo   = (const float*)d_in[2];
  // d_in[3] k_cache, d_in[4] v_cache: scatter+gather by identical indices == identity; unused
  const int* pos  = (const int*)d_in[5];
  // d_in[6] block_offsets: unused (see above)
  const int* winp = (const int*)d_in[7];
  float* out = (float*)d_out;

  u16* hsb = (u16*)d_ws;
  u16* wqb = hsb + (size_t)HID_*HID_;
  u16* wob = wqb + (size_t)QKVW_*HID_;
  u16* qkv = wob + (size_t)HID_*HID_;
  u16* att = qkv + (size_t)(B_*S_)*QKVW_;
  float2* tab = (float2*)(att + (size_t)(B_*S_)*HID_);

  cvt_kernel<<<2048, 256, 0, stream>>>(hs,   hsb, HID_*HID_/4);
  cvt_kernel<<<2048, 256, 0, stream>>>(wqkv, wqb, QKVW_*HID_/4);
  cvt_kernel<<<2048, 256, 0, stream>>>(wo,   wob, HID_*HID_/4);
  rope_table_kernel<<<(S_*64 + 255)/256, 256, 0, stream>>>(tab);
  gemm_bt<0><<<dim3(QKVW_/128, (B_*S_)/128), 256, 0, stream>>>(hsb, wqb, (void*)qkv, B_*S_, QKVW_, HID_);
  rope_apply_kernel<<<B_*S_, 256, 0, stream>>>(qkv, pos, tab);
  attn_kernel<<<dim3(S_/64, H_, B_), 256, 0, stream>>>(qkv, att, winp);
  gemm_bt<1><<<dim3(HID_/128, (B_*S_)/128), 256, 0, stream>>>(att, wob, (void*)out, B_*S_, HID_, HID_);
}

// Round 2
// 587.660 us; speedup vs baseline: 1.1876x; 1.1876x over previous
//
#include <hip/hip_runtime.h>
#include <hip/hip_bf16.h>
#include <stdint.h>

typedef unsigned short u16;
typedef __attribute__((ext_vector_type(8))) short short8;
typedef __attribute__((ext_vector_type(8))) unsigned short u16x8;
typedef __attribute__((ext_vector_type(4))) float f32x4;

#define B_    2
#define S_    2048
#define H_    32
#define HKV_  8
#define D_    128
#define HID_  4096
#define QKVW_ 6144

__device__ __forceinline__ u16 f2bf(float f){
  uint32_t b = __builtin_bit_cast(uint32_t, f);
  b += 0x7FFFu + ((b >> 16) & 1u);
  return (u16)(b >> 16);
}
__device__ __forceinline__ float bf2f(u16 h){
  uint32_t b = ((uint32_t)h) << 16;
  return __builtin_bit_cast(float, b);
}
__device__ __forceinline__ u16 bfc(float f){
  __hip_bfloat16 h = __float2bfloat16(f);
  return __builtin_bit_cast(u16, h);
}

__device__ __forceinline__ void gload16(const u16* g, u16* l){
  __builtin_amdgcn_global_load_lds((const __attribute__((address_space(1))) void*)g,
                                   (__attribute__((address_space(3))) void*)l, 16, 0, 0);
}

// ---------------- fp32 -> bf16 convert ----------------
__global__ void cvt_kernel(const float* __restrict__ src, u16* __restrict__ dst, int n4){
  int i = blockIdx.x * blockDim.x + threadIdx.x;
  int stride = gridDim.x * blockDim.x;
  for (; i < n4; i += stride){
    float4 v = reinterpret_cast<const float4*>(src)[i];
    union { u16 u[4]; unsigned long long ll; } o;
    o.u[0] = f2bf(v.x); o.u[1] = f2bf(v.y); o.u[2] = f2bf(v.z); o.u[3] = f2bf(v.w);
    reinterpret_cast<unsigned long long*>(dst)[i] = o.ll;
  }
}

// ---------------- RoPE table: tab[pos*64+p] = (cos, sin) ----------------
__global__ void rope_table_kernel(float2* __restrict__ tab){
  int idx = blockIdx.x * blockDim.x + threadIdx.x;
  if (idx >= S_ * 64) return;
  int pos = idx >> 6, p = idx & 63;
  float inv = powf(10000.0f, -(float)p / 64.0f);
  float ang = (float)pos * inv;
  tab[idx] = make_float2(cosf(ang), sinf(ang));
}

// ---------------- RoPE apply (in-place on bf16 qkv); Q gets scale*log2e folded ----------------
__global__ void rope_apply_kernel(u16* __restrict__ qkv, const int* __restrict__ pos_ids,
                                  const float2* __restrict__ tab){
  const float QS = 0.08838834764831845f * 1.4426950408889634f; // 1/sqrt(128) * log2(e)
  int t = blockIdx.x;
  int pos = pos_ids[t];
  const float2* tb = tab + pos * 64;
  u16* row = qkv + (size_t)t * QKVW_;
  for (int it = threadIdx.x; it < (H_ + HKV_) * 64; it += 256){
    int hh = it >> 6, p = it & 63;
    int base = (hh < H_) ? hh * D_ : HID_ + (hh - H_) * D_;
    float sc = (hh < H_) ? QS : 1.0f;
    float x1 = bf2f(row[base + p]);
    float x2 = bf2f(row[base + 64 + p]);
    float2 cs = tb[p];
    row[base + p]      = f2bf((x1 * cs.x - x2 * cs.y) * sc);
    row[base + 64 + p] = f2bf((x2 * cs.x + x1 * cs.y) * sc);
  }
}

// ---------------- bf16 GEMM: C[M][N] = A[M][K] * B[N][K]^T ----------------
template<int CF>
__global__ __launch_bounds__(256) void gemm_bt(const u16* __restrict__ A, const u16* __restrict__ B,
                                               void* __restrict__ Cv, int M, int N, int K){
  __shared__ u16 As[128*64];
  __shared__ u16 Bs[128*64];
  const int tid  = threadIdx.x;
  const int wave = tid >> 6, lane = tid & 63;
  const int hi = lane >> 4, lo = lane & 15;
  const int bn = blockIdx.x, bm = blockIdx.y;
  const int wm = (wave >> 1) * 64, wn = (wave & 1) * 64;
  f32x4 acc[4][4] = {};

  const u16* ap[4]; const u16* bp[4];
  u16* lA[4]; u16* lB[4];
  #pragma unroll
  for (int p = 0; p < 4; p++){
    int e   = p*2048 + wave*512 + lane*8;
    int row = e >> 6;
    int cs  = ((e >> 3) & 7) ^ (row & 7);
    ap[p] = A + (size_t)(bm*128 + row) * K + cs*8;
    bp[p] = B + (size_t)(bn*128 + row) * K + cs*8;
    lA[p] = &As[p*2048 + wave*512];
    lB[p] = &Bs[p*2048 + wave*512];
  }
  const int sw = lo & 7;
  const int nk = K >> 6;
  for (int t = 0; t < nk; t++){
    #pragma unroll
    for (int p = 0; p < 4; p++){
      gload16(ap[p], lA[p]);
      gload16(bp[p], lB[p]);
      ap[p] += 64; bp[p] += 64;
    }
    __syncthreads();
    #pragma unroll
    for (int kk = 0; kk < 2; kk++){
      short8 af[4], bf[4];
      int sz = ((kk*4 + hi) ^ sw) * 8;
      #pragma unroll
      for (int mt = 0; mt < 4; mt++) af[mt] = *(const short8*)&As[(wm + mt*16 + lo)*64 + sz];
      #pragma unroll
      for (int nt = 0; nt < 4; nt++) bf[nt] = *(const short8*)&Bs[(wn + nt*16 + lo)*64 + sz];
      #pragma unroll
      for (int mt = 0; mt < 4; mt++)
        #pragma unroll
        for (int nt = 0; nt < 4; nt++)
          acc[mt][nt] = __builtin_amdgcn_mfma_f32_16x16x32_bf16(af[mt], bf[nt], acc[mt][nt], 0, 0, 0);
    }
    __syncthreads();
  }
  #pragma unroll
  for (int mt = 0; mt < 4; mt++){
    int row = bm*128 + wm + mt*16 + 4*hi;
    #pragma unroll
    for (int nt = 0; nt < 4; nt++){
      int col = bn*128 + wn + nt*16 + lo;
      #pragma unroll
      for (int r = 0; r < 4; r++){
        if (CF == 0) ((u16*)Cv)[(size_t)(row + r)*N + col] = f2bf(acc[mt][nt][r]);
        else         ((float*)Cv)[(size_t)(row + r)*N + col] = acc[mt][nt][r];
      }
    }
  }
}

// ---------------- fused windowed-causal GQA flash attention (v2) ----------------
// block = (head h, qtile of 64 rows, batch b); 4 waves x 16 q-rows.
// Swapped QK^T: lane owns one q-row (q = qw + lo); j lives in acc rows (4*hi+r).
// KVBLK=64, double-buffered K (global_load_lds, XOR-swizzled source) + V^T (reg-staged).
__global__ __launch_bounds__(256) void attn_kernel(const u16* __restrict__ qkv, u16* __restrict__ out,
                                                   const int* __restrict__ winp){
  const int h = blockIdx.x, qt = blockIdx.y, b = blockIdx.z;
  const int hkv = h >> 2;            // G = 4
  const int q0 = qt * 64;
  const int tid = threadIdx.x, wave = tid >> 6, lane = tid & 63;
  const int lo = lane & 15, hi = lane >> 4;
  const int win = winp[0];

  __shared__ u16 Ks[2][64*128];      // K tiles, XOR-swizzled slots (linear dest, pre-swz src)
  __shared__ uint32_t VT[2][128*36]; // V^T tiles: VT[d][jpair] u32-packed, pitch 36
  __shared__ u16 Pl[4][16*72];       // per-wave P tile [q=16][j=64], pitch 72

  const int qw = q0 + wave*16;
  short8 qf[4];
  {
    const u16* qp = qkv + (size_t)(b*S_ + qw + lo)*QKVW_ + h*D_ + hi*8;
    #pragma unroll
    for (int c = 0; c < 4; c++) qf[c] = *(const short8*)(qp + c*32);
  }

  f32x4 accO[8] = {};
  float m_r = -3.0e38f, l_r = 0.0f;

  int js = q0 - (win - 1); if (js < 0) js = 0; js &= ~63;
  const int nt = (q0 + 64 - js) >> 6;

  const u16* Kg = qkv + (size_t)HID_ + hkv*D_;
  const u16* Vg = qkv + (size_t)HID_ + HKV_*D_ + hkv*D_;
  const int jp = tid & 31, d0 = (tid >> 5) * 16;

  // K staging geometry: dest linear, source slot XOR'd by (row&7) (rule #21 both-sides)
  const u16* ksrc[4];
  #pragma unroll
  for (int p = 0; p < 4; p++){
    int e = p*256 + tid;
    int row = e >> 4;
    int ss = (e & 15) ^ (row & 7);
    ksrc[p] = Kg + (size_t)(b*S_ + js + row)*QKVW_ + ss*8;
  }
  const u16* vsrc = Vg + (size_t)(b*S_ + js + 2*jp)*QKVW_ + d0;

  // prologue: stage chunk 0 into buffers 0
  u16x8 vr0, vr1, vr2, vr3;
  {
    #pragma unroll
    for (int p = 0; p < 4; p++) gload16(ksrc[p], &Ks[0][p*2048 + wave*512]);
    vr0 = *(const u16x8*)(vsrc);
    vr1 = *(const u16x8*)(vsrc + 8);
    vr2 = *(const u16x8*)(vsrc + QKVW_);
    vr3 = *(const u16x8*)(vsrc + QKVW_ + 8);
    #pragma unroll
    for (int i = 0; i < 8; i++){
      VT[0][(d0+i)*36 + jp]   = (uint32_t)vr0[i] | ((uint32_t)vr2[i] << 16);
      VT[0][(d0+8+i)*36 + jp] = (uint32_t)vr1[i] | ((uint32_t)vr3[i] << 16);
    }
  }
  __syncthreads();

  for (int t = 0; t < nt; t++){
    const int jc = js + t*64;
    const int cur = t & 1, nxt = cur ^ 1;
    const bool more = (t + 1 < nt);
    if (more){
      const size_t adv = (size_t)(t+1) * 64 * QKVW_;
      #pragma unroll
      for (int p = 0; p < 4; p++) gload16(ksrc[p] + adv, &Ks[nxt][p*2048 + wave*512]);
      const u16* vp = vsrc + adv;
      vr0 = *(const u16x8*)(vp);
      vr1 = *(const u16x8*)(vp + 8);
      vr2 = *(const u16x8*)(vp + QKVW_);
      vr3 = *(const u16x8*)(vp + QKVW_ + 8);
    }
    if (jc <= qw + 15 && jc + 63 >= qw - win + 1){
      // QK^T swapped: A=K (rows j), B=Q (cols q) -> s[jt] rows j=4hi+r, col q=lo
      f32x4 s[4] = {};
      #pragma unroll
      for (int jt = 0; jt < 4; jt++)
        #pragma unroll
        for (int c = 0; c < 4; c++){
          short8 kf = *(const short8*)&Ks[cur][(jt*16+lo)*128 + (((c*4+hi) ^ (lo & 7)) * 8)];
          s[jt] = __builtin_amdgcn_mfma_f32_16x16x32_bf16(kf, qf[c], s[jt], 0, 0, 0);
        }
      const int qa = qw + lo;
      const bool fullv = (jc + 63 <= qw) && (jc >= qw + 16 - win);
      if (!fullv){
        #pragma unroll
        for (int jt = 0; jt < 4; jt++)
          #pragma unroll
          for (int r = 0; r < 4; r++){
            int j = jc + jt*16 + 4*hi + r;
            if (j > qa || qa - j >= win) s[jt][r] = -3.0e38f;
          }
      }
      // row max: 15 in-lane + 2 shfl (lanes lo, lo+16, lo+32, lo+48 share q-row)
      float mx = s[0][0];
      #pragma unroll
      for (int jt = 0; jt < 4; jt++)
        #pragma unroll
        for (int r = 0; r < 4; r++) mx = fmaxf(mx, s[jt][r]);
      mx = fmaxf(mx, __shfl_xor(mx, 16));
      mx = fmaxf(mx, __shfl_xor(mx, 32));
      // defer-max (T13): rescale only when growth > 8 (log2 domain)
      if (__any(mx > m_r + 8.0f)){
        float mn = fmaxf(m_r, mx);
        float al = exp2f(m_r - mn);
        m_r = mn; l_r *= al;
        float a0 = __shfl(al, 4*hi+0), a1 = __shfl(al, 4*hi+1);
        float a2 = __shfl(al, 4*hi+2), a3 = __shfl(al, 4*hi+3);
        #pragma unroll
        for (int dt = 0; dt < 8; dt++){
          accO[dt][0] *= a0; accO[dt][1] *= a1;
          accO[dt][2] *= a2; accO[dt][3] *= a3;
        }
      }
      float ps = 0.f;
      #pragma unroll
      for (int jt = 0; jt < 4; jt++){
        float p0, p1, p2, p3;
        if (fullv){
          p0 = exp2f(s[jt][0] - m_r); p1 = exp2f(s[jt][1] - m_r);
          p2 = exp2f(s[jt][2] - m_r); p3 = exp2f(s[jt][3] - m_r);
        } else {
          p0 = s[jt][0] > -1e37f ? exp2f(s[jt][0] - m_r) : 0.f;
          p1 = s[jt][1] > -1e37f ? exp2f(s[jt][1] - m_r) : 0.f;
          p2 = s[jt][2] > -1e37f ? exp2f(s[jt][2] - m_r) : 0.f;
          p3 = s[jt][3] > -1e37f ? exp2f(s[jt][3] - m_r) : 0.f;
        }
        ps += (p0 + p1) + (p2 + p3);
        uint32_t w0 = (uint32_t)bfc(p0) | ((uint32_t)bfc(p1) << 16);
        uint32_t w1 = (uint32_t)bfc(p2) | ((uint32_t)bfc(p3) << 16);
        *(uint64_t*)&Pl[wave][lo*72 + jt*16 + 4*hi] = (uint64_t)w0 | ((uint64_t)w1 << 32);
      }
      ps += __shfl_xor(ps, 16);
      ps += __shfl_xor(ps, 32);
      l_r += ps;
      // PV: A = P[q=lo][j], B = V^T (cols d=lo); acc rows q=4hi+r, col d=lo
      short8 pa0 = *(const short8*)&Pl[wave][lo*72 + hi*8];
      short8 pa1 = *(const short8*)&Pl[wave][lo*72 + 32 + hi*8];
      const u16* VT16 = (const u16*)&VT[cur][0];
      #pragma unroll
      for (int dt = 0; dt < 8; dt++){
        short8 vf0 = *(const short8*)&VT16[(dt*16+lo)*72 + hi*8];
        short8 vf1 = *(const short8*)&VT16[(dt*16+lo)*72 + 32 + hi*8];
        accO[dt] = __builtin_amdgcn_mfma_f32_16x16x32_bf16(pa0, vf0, accO[dt], 0, 0, 0);
        accO[dt] = __builtin_amdgcn_mfma_f32_16x16x32_bf16(pa1, vf1, accO[dt], 0, 0, 0);
      }
    }
    if (more){
      // late half of async-STAGE split (T14): write next V^T after compute
      #pragma unroll
      for (int i = 0; i < 8; i++){
        VT[nxt][(d0+i)*36 + jp]   = (uint32_t)vr0[i] | ((uint32_t)vr2[i] << 16);
        VT[nxt][(d0+8+i)*36 + jp] = (uint32_t)vr1[i] | ((uint32_t)vr3[i] << 16);
      }
      __syncthreads();
    }
  }
  // epilogue: l lives at lane (q & 15); fetch per acc-row via shfl
  #pragma unroll
  for (int r = 0; r < 4; r++){
    float lr = __shfl(l_r, 4*hi + r);
    float invl = 1.0f / lr;
    int trow = b*S_ + qw + 4*hi + r;
    #pragma unroll
    for (int dt = 0; dt < 8; dt++)
      out[(size_t)trow*HID_ + h*D_ + dt*16 + lo] = f2bf(accO[dt][r] * invl);
  }
}

extern "C" void kernel_launch(void* const* d_in, const int* in_sizes, int n_in,
                              void* d_out, int out_size, void* d_ws, size_t ws_size,
                              hipStream_t stream) {
  const float* hs   = (const float*)d_in[0];
  const float* wqkv = (const float*)d_in[1];
  const float* wo   = (const float*)d_in[2];
  const int* pos  = (const int*)d_in[5];
  const int* winp = (const int*)d_in[7];
  float* out = (float*)d_out;

  u16* hsb = (u16*)d_ws;
  u16* wqb = hsb + (size_t)HID_*HID_;
  u16* wob = wqb + (size_t)QKVW_*HID_;
  u16* qkv = wob + (size_t)HID_*HID_;
  u16* att = qkv + (size_t)(B_*S_)*QKVW_;
  float2* tab = (float2*)(att + (size_t)(B_*S_)*HID_);

  cvt_kernel<<<2048, 256, 0, stream>>>(hs,   hsb, HID_*HID_/4);
  cvt_kernel<<<2048, 256, 0, stream>>>(wqkv, wqb, QKVW_*HID_/4);
  cvt_kernel<<<2048, 256, 0, stream>>>(wo,   wob, HID_*HID_/4);
  rope_table_kernel<<<(S_*64 + 255)/256, 256, 0, stream>>>(tab);
  gemm_bt<0><<<dim3(QKVW_/128, (B_*S_)/128), 256, 0, stream>>>(hsb, wqb, (void*)qkv, B_*S_, QKVW_, HID_);
  rope_apply_kernel<<<B_*S_, 256, 0, stream>>>(qkv, pos, tab);
  attn_kernel<<<dim3(H_, S_/64, B_), 256, 0, stream>>>(qkv, att, winp);
  gemm_bt<1><<<dim3(HID_/128, (B_*S_)/128), 256, 0, stream>>>(att, wob, (void*)out, B_*S_, HID_, HID_);
}